// Round 13
// baseline (652.024 us; speedup 1.0000x reference)
//
#include <hip/hip_runtime.h>

// EncoderDecoderLSTM, round 13.
// 512 blocks x 16 rows, NT=256 (4 waves), launch_bounds(256,2) -> 256-reg
// budget: ALL weights+biases in registers, zero spill. Each thread owns 4
// elements/layer (4 contiguous cols) -> 4-way ILP per wave at 2 waves/SIMD,
// h-store is one ds_write_b64. Same superphase/barrier structure as R12.

#define TT  336
#define HZN 168
#define NT  256
#define ROWS 16
#define XP  340
#define LN2E 1.44269504088896340736f
#define K2  2.88539008177792681472f   // 2*log2(e)

typedef short s8v __attribute__((ext_vector_type(8)));
typedef float f4v __attribute__((ext_vector_type(4)));
typedef float f2v __attribute__((ext_vector_type(2)));

#define MF(wf, hf, c) __builtin_amdgcn_mfma_f32_16x16x32_bf16((wf), (hf), (c), 0, 0, 0)

__device__ __forceinline__ short bf16rne(float f){
  unsigned u = __float_as_uint(f);
  return (short)((u + 0x7fffu + ((u >> 16) & 1u)) >> 16);
}
__device__ __forceinline__ f2v prcp(f2v d){
  return f2v{__builtin_amdgcn_rcpf(d.x), __builtin_amdgcn_rcpf(d.y)};
}
__device__ __forceinline__ f2v pexp2(f2v d){
  return f2v{__builtin_amdgcn_exp2f(d.x), __builtin_amdgcn_exp2f(d.y)};
}

// W fragment, PRE-SCALED by log2(e), permuted m-rows for NT=256:
// mm -> gate row (mm&3)*64 + [w*16 + 4*(mm>>2) + mt]
__device__ __forceinline__ s8v ldW(const float* __restrict__ Wm, int w, int l,
                                   int mt, int kt){
  int mm   = l & 15;
  int grow = (mm & 3)*64 + w*16 + 4*(mm >> 2) + mt;
  int k0   = kt*32 + (l >> 4)*8;
  const float* p = Wm + grow*64 + k0;
  float4 q0 = *(const float4*)(p);
  float4 q1 = *(const float4*)(p + 4);
  s8v v;
  v[0]=bf16rne(q0.x*LN2E); v[1]=bf16rne(q0.y*LN2E);
  v[2]=bf16rne(q0.z*LN2E); v[3]=bf16rne(q0.w*LN2E);
  v[4]=bf16rne(q1.x*LN2E); v[5]=bf16rne(q1.y*LN2E);
  v[6]=bf16rne(q1.z*LN2E); v[7]=bf16rne(q1.w*LN2E);
  return v;
}

// packed pointwise for two elements; gates PRE-SCALED by log2(e).
__device__ __forceinline__ void pwise2(f4v aA, f4v aB, f2v& c2,
                                       float& hA, float& hB){
  f2v i2{aA[0], aB[0]}, f2{aA[1], aB[1]}, g2{aA[2], aB[2]}, o2{aA[3], aB[3]};
  f2v ei = pexp2(-i2);
  f2v ef = pexp2(-f2);
  f2v eg = pexp2(g2 + g2);
  f2v eo = pexp2(-o2);
  f2v ig = (eg - 1.f) * prcp((1.f + ei) * (1.f + eg));
  f2v cn = c2 * prcp(1.f + ef) + ig;
  f2v ec = pexp2(cn * K2);
  f2v h  = (ec - 1.f) * prcp((1.f + eo) * (1.f + ec));
  c2 = cn;
  hA = h.x; hB = h.y;
}

// store lane's four contiguous h cols (c0 ≡ 0 mod 4) as packed bf16 (8B)
__device__ __forceinline__ void stH4(short* dst, float h0, float h1,
                                     float h2, float h3){
  unsigned pk0, pk1;
  asm("v_cvt_pk_bf16_f32 %0, %1, %2" : "=v"(pk0) : "v"(h0), "v"(h1));
  asm("v_cvt_pk_bf16_f32 %0, %1, %2" : "=v"(pk1) : "v"(h2), "v"(h3));
  *(uint2*)dst = uint2{pk0, pk1};
}

// ---- encoder superphase: L1(t) then (DO_L0 ? L0(t+1) : skip), 1 barrier ----
#define ENC_SUPER(P, t, DO_L0) {                                            \
  const short* h0R  = hS + (P)*2048;                                        \
  short*       h0Wr = hS + ((P)^1)*2048;                                    \
  const short* h1R  = hS + 4096 + (P)*2048;                                 \
  short*       h1Wr = hS + 4096 + ((P)^1)*2048;                             \
  s8v g00 = *(const s8v*)(h0R + lo0), g01 = *(const s8v*)(h0R + lo1);       \
  {                                                                         \
    s8v g10 = *(const s8v*)(h1R + lo0), g11 = *(const s8v*)(h1R + lo1);     \
    f4v aL[4];                                                              \
    _Pragma("unroll")                                                       \
    for (int mt=0; mt<4; mt++){                                             \
      aL[mt] = bE1[mt];                                                     \
      aL[mt] = MF(Wih1[mt][0], g00, aL[mt]);                                \
      aL[mt] = MF(Wih1[mt][1], g01, aL[mt]);                                \
      aL[mt] = MF(Whh1[mt][0], g10, aL[mt]);                                \
      aL[mt] = MF(Whh1[mt][1], g11, aL[mt]);                                \
    }                                                                       \
    float ha, hb, hc, hd;                                                   \
    pwise2(aL[0], aL[1], c1s01, ha, hb);                                    \
    pwise2(aL[2], aL[3], c1s23, hc, hd);                                    \
    stH4(h1Wr + so, ha, hb, hc, hd);                                        \
  }                                                                         \
  if (DO_L0){                                                               \
    float xv = xs[b*XP + (t) + 1];                                          \
    f4v aL[4];                                                              \
    _Pragma("unroll")                                                       \
    for (int mt=0; mt<4; mt++){                                             \
      aL[mt] = bE0[mt] + wx[mt]*xv;                                         \
      aL[mt] = MF(Whh0[mt][0], g00, aL[mt]);                                \
      aL[mt] = MF(Whh0[mt][1], g01, aL[mt]);                                \
    }                                                                       \
    float ha, hb, hc, hd;                                                   \
    pwise2(aL[0], aL[1], c0s01, ha, hb);                                    \
    pwise2(aL[2], aL[3], c0s23, hc, hd);                                    \
    stH4(h0Wr + so, ha, hb, hc, hd);                                        \
  }                                                                         \
  __syncthreads();                                                          \
}

// ---- decoder step: 2 barriers; h1 fragments loaded once, reused in B ----
#define DEC_STEP(Q, s) {                                                    \
  const short* h0R  = hS + (Q)*2048;                                        \
  short*       h0Wr = hS + ((Q)^1)*2048;                                    \
  const short* h1R  = hS + 4096 + ((Q)^1)*2048;                             \
  short*       h1Wr = hS + 4096 + (Q)*2048;                                 \
  s8v e0 = *(const s8v*)(h1R + lo0), e1 = *(const s8v*)(h1R + lo1);         \
  {                                                                         \
    s8v f0 = *(const s8v*)(h0R + lo0), f1 = *(const s8v*)(h0R + lo1);       \
    f4v aL[4];                                                              \
    _Pragma("unroll")                                                       \
    for (int mt=0; mt<4; mt++){                                             \
      aL[mt] = bD0[mt];                                                     \
      aL[mt] = MF(Whh0[mt][0], f0, aL[mt]);                                 \
      aL[mt] = MF(Whh0[mt][1], f1, aL[mt]);                                 \
    }                                                                       \
    if ((s) > 0){                                                           \
      _Pragma("unroll")                                                     \
      for (int mt=0; mt<4; mt++){                                           \
        aL[mt] = MF(Dih0[mt][0], e0, aL[mt]);                               \
        aL[mt] = MF(Dih0[mt][1], e1, aL[mt]);                               \
      }                                                                     \
    }                                                                       \
    float ha, hb, hc, hd;                                                   \
    pwise2(aL[0], aL[1], c0s01, ha, hb);                                    \
    pwise2(aL[2], aL[3], c0s23, hc, hd);                                    \
    stH4(h0Wr + so, ha, hb, hc, hd);                                        \
  }                                                                         \
  __syncthreads();                                                          \
  {                                                                         \
    s8v g0 = *(const s8v*)(h0Wr + lo0), g1 = *(const s8v*)(h0Wr + lo1);     \
    f4v aL[4];                                                              \
    _Pragma("unroll")                                                       \
    for (int mt=0; mt<4; mt++){                                             \
      aL[mt] = bD1[mt];                                                     \
      aL[mt] = MF(Wih1[mt][0], g0, aL[mt]);                                 \
      aL[mt] = MF(Wih1[mt][1], g1, aL[mt]);                                 \
      aL[mt] = MF(Whh1[mt][0], e0, aL[mt]);                                 \
      aL[mt] = MF(Whh1[mt][1], e1, aL[mt]);                                 \
    }                                                                       \
    float ha, hb, hc, hd;                                                   \
    pwise2(aL[0], aL[1], c1s01, ha, hb);                                    \
    pwise2(aL[2], aL[3], c1s23, hc, hd);                                    \
    stH4(h1Wr + so, ha, hb, hc, hd);                                        \
    float pr = ha*fcw[0] + hb*fcw[1] + hc*fcw[2] + hd*fcw[3];               \
    pr += __shfl_xor(pr, 16); pr += __shfl_xor(pr, 32);                     \
    if (l < 16) fcred[l*5 + w] = pr;                                        \
  }                                                                         \
  __syncthreads();                                                          \
  if (tid < 16){                                                            \
    float sm2 = fcb0;                                                       \
    _Pragma("unroll")                                                       \
    for (int j=0; j<4; j++) sm2 += fcred[tid*5 + j];                        \
    out[(size_t)(brow0 + tid)*HZN + (s)] = sm2;                             \
  }                                                                         \
}

__global__ __launch_bounds__(NT, 2)
void edlstm_kernel(const float* __restrict__ x,
  const float* __restrict__ eWih0, const float* __restrict__ eWhh0,
  const float* __restrict__ ebih0, const float* __restrict__ ebhh0,
  const float* __restrict__ eWih1, const float* __restrict__ eWhh1,
  const float* __restrict__ ebih1, const float* __restrict__ ebhh1,
  const float* __restrict__ dWih0, const float* __restrict__ dWhh0,
  const float* __restrict__ dbih0, const float* __restrict__ dbhh0,
  const float* __restrict__ dWih1, const float* __restrict__ dWhh1,
  const float* __restrict__ dbih1, const float* __restrict__ dbhh1,
  const float* __restrict__ fcW, const float* __restrict__ fcb,
  float* __restrict__ out)
{
  __shared__ float xs[ROWS*XP];
  __shared__ short hS[8192];         // h0[2], h1[2] bf16 swizzled (1KB each used)
  __shared__ float fcred[16*5];

  const int tid = threadIdx.x;
  const int l   = tid & 63;
  const int w   = tid >> 6;          // wave 0..3
  const int b   = l & 15;
  const int lq  = l >> 4;            // 0..3
  const int c0  = w*16 + 4*lq;       // 4 contiguous cols, c0 % 4 == 0
  const int brow0 = blockIdx.x * ROWS;

  // loop-invariant swizzled lane offsets (shorts)
  const int lo0 = b*64 + ((lq       ^ (b & 7)) << 3);
  const int lo1 = b*64 + (((4 + lq) ^ (b & 7)) << 3);
  const int so  = b*64 + (((c0 >> 3) ^ (b & 7)) << 3) + (c0 & 7);

  { // zero h buffers: 1024 int4
    int4* hz = (int4*)hS;
    #pragma unroll
    for (int k=0; k<4; k++) hz[k*NT + tid] = int4{0,0,0,0};
  }
  #pragma unroll
  for (int k=0; k<6; k++){           // stage x: 16 rows x 84 float4
    int idx = k*NT + tid;
    if (idx < ROWS*84){
      int row = idx / 84;
      int c   = idx - row*84;
      *(float4*)(xs + row*XP + c*4) =
        *(const float4*)(x + (size_t)(brow0+row)*TT + c*4);
    }
  }

  // encoder biases + wx in registers, pre-scaled by log2(e)
  f4v bE0[4], bE1[4], wx[4];
  #pragma unroll
  for (int mt=0; mt<4; mt++)
    #pragma unroll
    for (int g2=0; g2<4; g2++){
      int j = g2*64 + c0 + mt;
      bE0[mt][g2] = (ebih0[j] + ebhh0[j]) * LN2E;
      bE1[mt][g2] = (ebih1[j] + ebhh1[j]) * LN2E;
      wx[mt][g2]  = eWih0[j] * LN2E;
    }

  s8v Whh0[4][2], Wih1[4][2], Whh1[4][2];
  #pragma unroll
  for (int mt=0; mt<4; mt++)
    #pragma unroll
    for (int kt=0; kt<2; kt++){
      Whh0[mt][kt] = ldW(eWhh0, w, l, mt, kt);
      Wih1[mt][kt] = ldW(eWih1, w, l, mt, kt);
      Whh1[mt][kt] = ldW(eWhh1, w, l, mt, kt);
    }

  f2v c0s01 = {0.f,0.f}, c0s23 = {0.f,0.f};
  f2v c1s01 = {0.f,0.f}, c1s23 = {0.f,0.f};
  __syncthreads();

  // ---- encoder prologue: L0(0) = bias + wx*x0 (h0(-1)=0) -> h0buf[1] ----
  {
    float xv = xs[b*XP];
    f4v aL[4];
    float ha, hb, hc, hd;
    #pragma unroll
    for (int mt=0; mt<4; mt++) aL[mt] = bE0[mt] + wx[mt]*xv;
    pwise2(aL[0], aL[1], c0s01, ha, hb);
    pwise2(aL[2], aL[3], c0s23, hc, hd);
    stH4(hS + 2048 + so, ha, hb, hc, hd);
    __syncthreads();
  }

  // ---- encoder: 336 superphases, 1 barrier each ----
  for (int k=0; k<167; k++){
    ENC_SUPER(1, 2*k,   1);
    ENC_SUPER(0, 2*k+1, 1);
  }
  ENC_SUPER(1, 334, 1);
  ENC_SUPER(0, 335, 0);
  // now: h0(335) in h0buf[0], h1(335) in h1buf[1]

  // ---- decoder weights + biases (registers; 256-reg budget) ----
  s8v Dih0[4][2];
  #pragma unroll
  for (int mt=0; mt<4; mt++)
    #pragma unroll
    for (int kt=0; kt<2; kt++){
      Dih0[mt][kt] = ldW(dWih0, w, l, mt, kt);
      Whh0[mt][kt] = ldW(dWhh0, w, l, mt, kt);
      Wih1[mt][kt] = ldW(dWih1, w, l, mt, kt);
      Whh1[mt][kt] = ldW(dWhh1, w, l, mt, kt);
    }
  f4v bD0[4], bD1[4];
  #pragma unroll
  for (int mt=0; mt<4; mt++)
    #pragma unroll
    for (int g2=0; g2<4; g2++){
      int j = g2*64 + c0 + mt;
      bD0[mt][g2] = (dbih0[j] + dbhh0[j]) * LN2E;
      bD1[mt][g2] = (dbih1[j] + dbhh1[j]) * LN2E;
    }
  f4v fcw;
  #pragma unroll
  for (int mt=0; mt<4; mt++) fcw[mt] = fcW[c0 + mt];
  const float fcb0 = fcb[0];

  // ---- decoder: 168 steps ----
  for (int k=0; k<84; k++){
    DEC_STEP(0, 2*k);
    DEC_STEP(1, 2*k+1);
  }
}

extern "C" void kernel_launch(void* const* d_in, const int* in_sizes, int n_in,
                              void* d_out, int out_size, void* d_ws, size_t ws_size,
                              hipStream_t stream)
{
  (void)in_sizes; (void)n_in; (void)d_ws; (void)ws_size; (void)out_size;
  const float* x     = (const float*)d_in[0];
  const float* eWih0 = (const float*)d_in[1];
  const float* eWhh0 = (const float*)d_in[2];
  const float* ebih0 = (const float*)d_in[3];
  const float* ebhh0 = (const float*)d_in[4];
  const float* eWih1 = (const float*)d_in[5];
  const float* eWhh1 = (const float*)d_in[6];
  const float* ebih1 = (const float*)d_in[7];
  const float* ebhh1 = (const float*)d_in[8];
  const float* dWih0 = (const float*)d_in[9];
  const float* dWhh0 = (const float*)d_in[10];
  const float* dbih0 = (const float*)d_in[11];
  const float* dbhh0 = (const float*)d_in[12];
  const float* dWih1 = (const float*)d_in[13];
  const float* dWhh1 = (const float*)d_in[14];
  const float* dbih1 = (const float*)d_in[15];
  const float* dbhh1 = (const float*)d_in[16];
  const float* fcW   = (const float*)d_in[17];
  const float* fcb   = (const float*)d_in[18];
  float* out = (float*)d_out;

  edlstm_kernel<<<dim3(512), dim3(NT), 0, stream>>>(
      x, eWih0, eWhh0, ebih0, ebhh0, eWih1, eWhh1, ebih1, ebhh1,
      dWih0, dWhh0, dbih0, dbhh0, dWih1, dWhh1, dbih1, dbhh1,
      fcW, fcb, out);
}